// Round 4
// baseline (448.713 us; speedup 1.0000x reference)
//
#include <hip/hip_runtime.h>
#include <hip/hip_bf16.h>
#include <stdint.h>

#define N_SAMP 8192
#define D_TOW  128
#define D_HID  128

typedef __bf16 bf16x8 __attribute__((ext_vector_type(8)));
typedef float  f32x4  __attribute__((ext_vector_type(4)));
typedef float  f32x2  __attribute__((ext_vector_type(2)));

__device__ __forceinline__ ushort f2bf(float f) {
  union { float f; uint32_t u; } c; c.f = f;
  uint32_t u = c.u;
  return (ushort)((u + 0x7FFFu + ((u >> 16) & 1u)) >> 16);  // RNE
}

// sigmoid via raw HW ops: v_exp_f32 + v_rcp_f32.
__device__ __forceinline__ float fast_sigmoid(float p) {
  float e = __builtin_amdgcn_exp2f(p * -1.442695040888963f);
  return __builtin_amdgcn_rcpf(1.0f + e);
}

// fp32 -> bf16 convert. W0 is pre-scaled by -log2(e) so the towers MFMA
// directly produces exp2 arguments. x path writes a per-block "saw
// non-binary" flag UNCONDITIONALLY (no memset needed). 1024-thread blocks
// -> flagArr is 256 ints.
__global__ __launch_bounds__(1024) void prep_kernel(
    const float* __restrict__ x, const float* __restrict__ w0,
    ushort* __restrict__ xb, ushort* __restrict__ w0b,
    int* __restrict__ flagArr) {
  const int NX4 = (N_SAMP * D_TOW) / 4;  // 262144 -> x-blocks are bid 0..255
  int bid = blockIdx.x;
  int tid = threadIdx.x;
  int t = bid * 1024 + tid;
  if (bid < 256) {
    __shared__ int sbad;
    if (tid == 0) sbad = 0;
    float4 v = ((const float4*)x)[t];
    bool bad = !(((v.x == 0.f) || (v.x == 1.f)) &&
                 ((v.y == 0.f) || (v.y == 1.f)) &&
                 ((v.z == 0.f) || (v.z == 1.f)) &&
                 ((v.w == 0.f) || (v.w == 1.f)));
    ushort4 o;
    o.x = f2bf(v.x); o.y = f2bf(v.y); o.z = f2bf(v.z); o.w = f2bf(v.w);
    ((ushort4*)xb)[t] = o;
    __syncthreads();
    if (__ballot(bad) != 0ull && (tid & 63) == 0) sbad = 1;
    __syncthreads();
    if (tid == 0) flagArr[bid] = sbad;
  } else {
    const float c = -1.442695040888963f;
    int j = t - NX4;
    float4 v = ((const float4*)w0)[j];
    ushort4 o;
    o.x = f2bf(c * v.x); o.y = f2bf(c * v.y);
    o.z = f2bf(c * v.z); o.w = f2bf(c * v.w);
    ((ushort4*)w0b)[j] = o;
  }
}

__device__ __forceinline__ void g2l16(const void* g, void* l) {
  __builtin_amdgcn_global_load_lds(
      (const __attribute__((address_space(1))) void*)g,
      (__attribute__((address_space(3))) void*)l, 16, 0, 0);
}

// One block = one tower k x one 256-row chunk of samples (512 thr, 8 waves:
// 4 n-quadrants x 2 h-halves; per-wave tile identical to the 256-thr R3
// version). vs R3: W0_k staged once per 256 samples (W L2 traffic halved,
// 512->384 MB total) and LDS = 32K sX + 16K sW + 2K sRed ~= 50.3 KB ->
// 3 blocks/CU = 24 waves/CU (was 16). R3's counters showed the four pipe
// terms (MFMA 16, LDS 15, VALU+trans 15, L2-staging 15 us) running almost
// serially -- more resident waves + less staging is the overlap lever.
// K staged in TWO halves of (32+16) KB; LDS rows are 64 bf16 (8x16B slots),
// slot holds global chunk slot^(row&7) -> conflict-free ds_read_b128.
// Block mapping: per XCD, k is the FAST index -> 16 towers sharing an
// n-chunk run concurrently -> out[n][k0..k0+15] write-merges in L2.
__global__ __launch_bounds__(512, 6) void towers_kernel(
    const ushort* __restrict__ xb, const ushort* __restrict__ w0b,
    const float* __restrict__ b0, const float* __restrict__ w1,
    const float* __restrict__ b1, const int* __restrict__ flagArr,
    float* __restrict__ out) {
  __shared__ __align__(16) ushort sX[256 * 64];  // 32 KB
  __shared__ __align__(16) ushort sW[128 * 64];  // 16 KB
  __shared__ float sRed[256][2];                 // 2 KB
  __shared__ int sBadW[8];

  int bid = blockIdx.x;          // 4096 blocks
  int xcd = bid & 7;
  int idx = bid >> 3;            // 0..511 per XCD
  int k  = xcd * 16 + (idx & 15);
  int n0 = (idx >> 4) * 256;

  int tid = threadIdx.x;
  int lane = tid & 63;
  int wave = tid >> 6;           // 0..7
  int q = lane >> 4;             // quad index (bits 4-5)
  int cl = lane & 15;

  const ushort* xg = xb + (size_t)n0 * 128;  // [256][128] row-major bf16
  const ushort* wg = w0b + k * (128 * 128);  // W0_k: [h][d] row-major bf16

  int R  = (wave >> 1) * 64;   // n-quadrant (0..3)
  int Ch = (wave & 1) * 64;    // h-half

  int rowl = lane >> 3;   // 0..7 within a 1KB staging chunk
  int slot = lane & 7;

  // Phase-0 staging issued first so latency hides under flag read +
  // bias load + acc init. X: 4 issues/wave (rows wave*32..+31);
  // W: 2 issues/wave (rows wave*16..+15).
#pragma unroll
  for (int i = 0; i < 4; ++i) {
    int row = wave * 32 + i * 8 + rowl;
    int c = slot ^ (row & 7);
    g2l16(xg + row * 128 + c * 8, (char*)sX + (wave * 32 + i * 8) * 128);
  }
#pragma unroll
  for (int i = 0; i < 2; ++i) {
    int row = wave * 16 + i * 8 + rowl;
    int c = slot ^ (row & 7);
    g2l16(wg + row * 128 + c * 8, (char*)sW + (wave * 16 + i * 8) * 128);
  }

  // Binary-flag OR-reduce (256 ints; waves 4..7 re-read 0..255 harmlessly).
  int anyb = flagArr[tid & 255];
  unsigned long long mb = __ballot(anyb != 0);
  if (lane == 0) sBadW[wave] = (mb != 0ull) ? 1 : 0;

  // acc init = -log2e * b0 (bias folded into MFMA accumulator).
  // C layout: col = n = R + nf*16 + cl ; row = h = Ch + hf*16 + q*4 + r.
  f32x4 acc[4][4];             // [hf][nf]
#pragma unroll
  for (int hf = 0; hf < 4; ++hf) {
    int h = k * 128 + Ch + hf * 16 + q * 4;
    f32x4 bbs = *(const f32x4*)&b0[h] * -1.442695040888963f;
#pragma unroll
    for (int nf = 0; nf < 4; ++nf)
      acc[hf][nf] = bbs;
  }

  // Row base byte-offsets (LDS row = 128 B).
  int aBase[4], bBase[4];
#pragma unroll
  for (int f = 0; f < 4; ++f) {
    aBase[f] = (Ch + f * 16 + cl) * 128;     // W row = h   (sW: 128 rows)
    bBase[f] = (R + f * 16 + cl) * 128;      // X row = n   (sX: 256 rows)
  }

#pragma unroll
  for (int kb = 0; kb < 2; ++kb) {
    __syncthreads();   // staged data visible (compiler drains vmcnt first)

#pragma unroll
    for (int t = 0; t < 2; ++t) {  // 2 x K=32 per phase
      int ch = ((t * 4 + q) ^ (cl & 7)) << 4;   // swizzled 16B slot offset
      bf16x8 a[4], b[4];
#pragma unroll
      for (int hf = 0; hf < 4; ++hf)
        a[hf] = *(const bf16x8*)((const char*)sW + aBase[hf] + ch);
#pragma unroll
      for (int nf = 0; nf < 4; ++nf)
        b[nf] = *(const bf16x8*)((const char*)sX + bBase[nf] + ch);
      __builtin_amdgcn_s_setprio(1);
#pragma unroll
      for (int hf = 0; hf < 4; ++hf)
#pragma unroll
        for (int nf = 0; nf < 4; ++nf)
          acc[hf][nf] = __builtin_amdgcn_mfma_f32_16x16x32_bf16(
              a[hf], b[nf], acc[hf][nf], 0, 0, 0);
      __builtin_amdgcn_s_setprio(0);
    }

    if (kb == 0) {
      __syncthreads();   // everyone done reading phase-0 LDS
      // Stage the second k-half [64..127] of both tiles.
#pragma unroll
      for (int i = 0; i < 4; ++i) {
        int row = wave * 32 + i * 8 + rowl;
        int c = slot ^ (row & 7);
        g2l16(xg + row * 128 + 64 + c * 8,
              (char*)sX + (wave * 32 + i * 8) * 128);
      }
#pragma unroll
      for (int i = 0; i < 2; ++i) {
        int row = wave * 16 + i * 8 + rowl;
        int c = slot ^ (row & 7);
        g2l16(wg + row * 128 + 64 + c * 8,
              (char*)sW + (wave * 16 + i * 8) * 128);
      }
    }
  }

  // Epilogue: sigmoid = rcp(1 + exp2(acc)); rcps paired (2 trans -> 1.5
  // per elem); mul/fma paths paired as f32x2 for v_pk_*_f32.
  f32x2 s2[4] = {{0.f, 0.f}, {0.f, 0.f}, {0.f, 0.f}, {0.f, 0.f}};
#pragma unroll
  for (int hf = 0; hf < 4; ++hf) {
    int h = k * 128 + Ch + hf * 16 + q * 4;
    f32x4 wv = *(const f32x4*)&w1[h];
    f32x2 wa = {wv[0], wv[1]};
    f32x2 wb = {wv[2], wv[3]};
#pragma unroll
    for (int nf = 0; nf < 4; ++nf) {
      f32x4 qv = acc[hf][nf];
      f32x2 dA = {1.0f + __builtin_amdgcn_exp2f(qv[0]),
                  1.0f + __builtin_amdgcn_exp2f(qv[1])};
      f32x2 dB = {1.0f + __builtin_amdgcn_exp2f(qv[2]),
                  1.0f + __builtin_amdgcn_exp2f(qv[3])};
      float rA = __builtin_amdgcn_rcpf(dA[0] * dA[1]);
      float rB = __builtin_amdgcn_rcpf(dB[0] * dB[1]);
      f32x2 cA = (f32x2){dA[1], dA[0]} * (f32x2){rA, rA};
      f32x2 cB = (f32x2){dB[1], dB[0]} * (f32x2){rB, rB};
      s2[nf] += wa * cA;
      s2[nf] += wb * cB;
    }
  }
  float s[4];
#pragma unroll
  for (int nf = 0; nf < 4; ++nf)
    s[nf] = s2[nf][0] + s2[nf][1];

#pragma unroll
  for (int m = 16; m <= 32; m <<= 1)
#pragma unroll
    for (int nf = 0; nf < 4; ++nf)
      s[nf] += __shfl_xor(s[nf], m, 64);

  if (q == 0) {
#pragma unroll
    for (int nf = 0; nf < 4; ++nf)
      sRed[R + nf * 16 + cl][wave & 1] = s[nf];
  }
  __syncthreads();

  if (tid < 256) {
    int anyBad = sBadW[0] | sBadW[1] | sBadW[2] | sBadW[3] |
                 sBadW[4] | sBadW[5] | sBadW[6] | sBadW[7];
    float v = sRed[tid][0] + sRed[tid][1] + b1[k];
    if (anyBad == 0) v = fast_sigmoid(v);  // binary-input path
    out[(size_t)(n0 + tid) * D_TOW + k] = v;
  }
}

extern "C" void kernel_launch(void* const* d_in, const int* in_sizes, int n_in,
                              void* d_out, int out_size, void* d_ws, size_t ws_size,
                              hipStream_t stream) {
  const float* x  = (const float*)d_in[0];
  const float* w0 = (const float*)d_in[1];
  const float* b0 = (const float*)d_in[2];
  const float* w1 = (const float*)d_in[3];
  const float* b1 = (const float*)d_in[4];
  float* out = (float*)d_out;

  char* ws = (char*)d_ws;
  int* flagArr = (int*)ws;                                   // 1 KB
  ushort* xb  = (ushort*)(ws + 4096);                        // 2 MB
  ushort* w0b = (ushort*)(ws + 4096 + N_SAMP * D_TOW * 2);   // 4 MB

  int total = (N_SAMP * D_TOW + D_TOW * D_HID * D_TOW) / 4;  // 786432 float4
  prep_kernel<<<total / 1024, 1024, 0, stream>>>(x, w0, xb, w0b, flagArr);

  towers_kernel<<<4096, 512, 0, stream>>>(xb, w0b, b0, w1, b1, flagArr, out);
}

// Round 5
// 202.947 us; speedup vs baseline: 2.2110x; 2.2110x over previous
//
#include <hip/hip_runtime.h>
#include <hip/hip_bf16.h>
#include <stdint.h>

#define N_SAMP 8192
#define D_TOW  128
#define D_HID  128

typedef __bf16 bf16x8 __attribute__((ext_vector_type(8)));
typedef float  f32x4  __attribute__((ext_vector_type(4)));
typedef float  f32x2  __attribute__((ext_vector_type(2)));

__device__ __forceinline__ ushort f2bf(float f) {
  union { float f; uint32_t u; } c; c.f = f;
  uint32_t u = c.u;
  return (ushort)((u + 0x7FFFu + ((u >> 16) & 1u)) >> 16);  // RNE
}

// sigmoid via raw HW ops: v_exp_f32 + v_rcp_f32.
__device__ __forceinline__ float fast_sigmoid(float p) {
  float e = __builtin_amdgcn_exp2f(p * -1.442695040888963f);
  return __builtin_amdgcn_rcpf(1.0f + e);
}

// fp32 -> bf16 convert. W0 is pre-scaled by -log2(e) so the towers MFMA
// directly produces exp2 arguments. x path writes a per-block "saw
// non-binary" flag UNCONDITIONALLY (no memset needed). 1024-thread blocks
// -> flagArr is 256 ints.
__global__ __launch_bounds__(1024) void prep_kernel(
    const float* __restrict__ x, const float* __restrict__ w0,
    ushort* __restrict__ xb, ushort* __restrict__ w0b,
    int* __restrict__ flagArr) {
  const int NX4 = (N_SAMP * D_TOW) / 4;  // 262144 -> x-blocks are bid 0..255
  int bid = blockIdx.x;
  int tid = threadIdx.x;
  int t = bid * 1024 + tid;
  if (bid < 256) {
    __shared__ int sbad;
    if (tid == 0) sbad = 0;
    float4 v = ((const float4*)x)[t];
    bool bad = !(((v.x == 0.f) || (v.x == 1.f)) &&
                 ((v.y == 0.f) || (v.y == 1.f)) &&
                 ((v.z == 0.f) || (v.z == 1.f)) &&
                 ((v.w == 0.f) || (v.w == 1.f)));
    ushort4 o;
    o.x = f2bf(v.x); o.y = f2bf(v.y); o.z = f2bf(v.z); o.w = f2bf(v.w);
    ((ushort4*)xb)[t] = o;
    __syncthreads();
    if (__ballot(bad) != 0ull && (tid & 63) == 0) sbad = 1;
    __syncthreads();
    if (tid == 0) flagArr[bid] = sbad;
  } else {
    const float c = -1.442695040888963f;
    int j = t - NX4;
    float4 v = ((const float4*)w0)[j];
    ushort4 o;
    o.x = f2bf(c * v.x); o.y = f2bf(c * v.y);
    o.z = f2bf(c * v.z); o.w = f2bf(c * v.w);
    ((ushort4*)w0b)[j] = o;
  }
}

__device__ __forceinline__ void g2l16(const void* g, void* l) {
  __builtin_amdgcn_global_load_lds(
      (const __attribute__((address_space(1))) void*)g,
      (__attribute__((address_space(3))) void*)l, 16, 0, 0);
}

// Stage one K-half (64 cols) of the X chunk and W0_k into LDS.
// LDS dest = uniform base + lane*16 (HW rule); XOR swizzle applied to the
// *global source* chunk: LDS[row][c] holds global chunk c^(row&7).
__device__ __forceinline__ void stage_half(
    const ushort* __restrict__ xg, const ushort* __restrict__ wg, int koff,
    ushort* sX, ushort* sW, int wave, int rowl, int slot) {
#pragma unroll
  for (int i = 0; i < 4; ++i) {
    int row = wave * 32 + i * 8 + rowl;
    int c = slot ^ (row & 7);
    int goff = row * 128 + koff + c * 8;
    int lbase = (wave * 32 + i * 8) * 128;
    g2l16(xg + goff, (char*)sX + lbase);
    g2l16(wg + goff, (char*)sW + lbase);
  }
}

// Two K=32 MFMA steps over the currently staged half.
__device__ __forceinline__ void mfma_half(
    const ushort* sW, const ushort* sX, const int* aBase, const int* bBase,
    int q, int cl, f32x4 acc[4][4]) {
#pragma unroll
  for (int t = 0; t < 2; ++t) {
    int ch = ((t * 4 + q) ^ (cl & 7)) << 4;   // swizzled 16B slot offset
    bf16x8 a[4], b[4];
#pragma unroll
    for (int hf = 0; hf < 4; ++hf)
      a[hf] = *(const bf16x8*)((const char*)sW + aBase[hf] + ch);
#pragma unroll
    for (int nf = 0; nf < 4; ++nf)
      b[nf] = *(const bf16x8*)((const char*)sX + bBase[nf] + ch);
    __builtin_amdgcn_s_setprio(1);
#pragma unroll
    for (int hf = 0; hf < 4; ++hf)
#pragma unroll
      for (int nf = 0; nf < 4; ++nf)
        acc[hf][nf] = __builtin_amdgcn_mfma_f32_16x16x32_bf16(
            a[hf], b[nf], acc[hf][nf], 0, 0, 0);
    __builtin_amdgcn_s_setprio(0);
  }
}

// PERSISTENT version of the R3 structure (R3 = 57.7 us, 4 blocks/CU,
// 64 VGPR + 64 AGPR = exactly the 4-waves/SIMD reg cap; R4's (512,6)
// spilled acc to scratch -> 640 MB HBM fetch, 7x regression).
// Grid 1024 = 4 blocks/CU; each block owns tower k (fixed -> W0_k L2-hot)
// and iterates 8 n-chunks. After the last MFMA of item j it ISSUES the
// global->LDS stage for item j+1, then runs item j's ~1000-cycle
// trans-heavy epilogue -- staging latency + barrier drain hide under it.
// Item order keeps 16 towers per n0 concurrent per XCD (L2 write-merge).
// 4 barriers/item, same LDS (33.5 KB) and regs as R3.
__global__ __launch_bounds__(256, 4) void towers_kernel(
    const ushort* __restrict__ xb, const ushort* __restrict__ w0b,
    const float* __restrict__ b0, const float* __restrict__ w1,
    const float* __restrict__ b1, const int* __restrict__ flagArr,
    float* __restrict__ out) {
  __shared__ __align__(16) ushort sX[128 * 64];  // 16 KB
  __shared__ __align__(16) ushort sW[128 * 64];  // 16 KB
  __shared__ float sRed[128][2];
  __shared__ int sBadW[4];

  int bid = blockIdx.x;          // 1024 blocks
  int xcd = bid & 7;
  int lb  = bid >> 3;            // 0..127 per XCD
  int k   = xcd * 16 + (lb & 15);
  int col = lb >> 4;             // 0..7

  int tid = threadIdx.x;
  int lane = tid & 63;
  int wave = tid >> 6;
  int q = lane >> 4;      // quad index (bits 4-5)
  int cl = lane & 15;
  int rowl = lane >> 3;   // 0..7 within a 1KB staging chunk
  int slot = lane & 7;

  const ushort* wg = w0b + k * (128 * 128);  // W0_k: [h][d] row-major bf16

  // Binary-flag OR-reduce (256 ints = 1 KB), once per block.
  int anyb = flagArr[tid];
  unsigned long long mb = __ballot(anyb != 0);
  if (lane == 0) sBadW[wave] = (mb != 0ull) ? 1 : 0;

  int R  = (wave >> 1) * 64;   // n-quadrant
  int Ch = (wave & 1) * 64;    // h-half

  // Row base byte-offsets (LDS row = 128 B), constant across items.
  int aBase[4], bBase[4];
#pragma unroll
  for (int f = 0; f < 4; ++f) {
    aBase[f] = (Ch + f * 16 + cl) * 128;     // W row = h
    bBase[f] = (R + f * 16 + cl) * 128;      // X row = n
  }

  const float cn = -1.442695040888963f;

  // Prologue: stage item 0, k-half 0.
  {
    const ushort* xg0 = xb + (size_t)col * (128 * 128);
    stage_half(xg0, wg, 0, sX, sW, wave, rowl, slot);
  }
  __syncthreads();   // compiler drains vmcnt -> item-0 kb0 visible

  for (int j = 0; j < 8; ++j) {
    int chunk = j * 8 + col;
    const ushort* xg = xb + (size_t)chunk * (128 * 128);
    int n0 = chunk * 128;

    // acc init = -log2e * b0 (bias folded into MFMA accumulator).
    // C layout: col = n = R + nf*16 + cl ; row = h = Ch + hf*16 + q*4 + r.
    f32x4 acc[4][4];             // [hf][nf]
#pragma unroll
    for (int hf = 0; hf < 4; ++hf) {
      int h = k * 128 + Ch + hf * 16 + q * 4;
      f32x4 bbs = *(const f32x4*)&b0[h] * cn;
#pragma unroll
      for (int nf = 0; nf < 4; ++nf)
        acc[hf][nf] = bbs;
    }

    mfma_half(sW, sX, aBase, bBase, q, cl, acc);   // K 0..63
    __syncthreads();                               // kb0 reads done
    stage_half(xg, wg, 64, sX, sW, wave, rowl, slot);
    __syncthreads();                               // kb1 visible (vmcnt drain)
    mfma_half(sW, sX, aBase, bBase, q, cl, acc);   // K 64..127
    __syncthreads();                               // kb1 reads done

    // Issue NEXT item's kb0 stage now; its latency + the barrier drain
    // hide under this item's trans-heavy epilogue.
    if (j < 7) {
      const ushort* xgn = xb + (size_t)(chunk + 8) * (128 * 128);
      stage_half(xgn, wg, 0, sX, sW, wave, rowl, slot);
    }

    // Epilogue: sigmoid = rcp(1 + exp2(acc)); rcps paired (1.5 trans/elem);
    // mul/fma paths paired as f32x2 for v_pk_*_f32.
    f32x2 s2[4] = {{0.f, 0.f}, {0.f, 0.f}, {0.f, 0.f}, {0.f, 0.f}};
#pragma unroll
    for (int hf = 0; hf < 4; ++hf) {
      int h = k * 128 + Ch + hf * 16 + q * 4;
      f32x4 wv = *(const f32x4*)&w1[h];
      f32x2 wa = {wv[0], wv[1]};
      f32x2 wb = {wv[2], wv[3]};
#pragma unroll
      for (int nf = 0; nf < 4; ++nf) {
        f32x4 qv = acc[hf][nf];
        f32x2 dA = {1.0f + __builtin_amdgcn_exp2f(qv[0]),
                    1.0f + __builtin_amdgcn_exp2f(qv[1])};
        f32x2 dB = {1.0f + __builtin_amdgcn_exp2f(qv[2]),
                    1.0f + __builtin_amdgcn_exp2f(qv[3])};
        float rA = __builtin_amdgcn_rcpf(dA[0] * dA[1]);
        float rB = __builtin_amdgcn_rcpf(dB[0] * dB[1]);
        f32x2 cA = (f32x2){dA[1], dA[0]} * (f32x2){rA, rA};
        f32x2 cB = (f32x2){dB[1], dB[0]} * (f32x2){rB, rB};
        s2[nf] += wa * cA;
        s2[nf] += wb * cB;
      }
    }
    float s[4];
#pragma unroll
    for (int nf = 0; nf < 4; ++nf)
      s[nf] = s2[nf][0] + s2[nf][1];

#pragma unroll
    for (int m = 16; m <= 32; m <<= 1)
#pragma unroll
      for (int nf = 0; nf < 4; ++nf)
        s[nf] += __shfl_xor(s[nf], m, 64);

    if (q == 0) {
#pragma unroll
      for (int nf = 0; nf < 4; ++nf)
        sRed[R + nf * 16 + cl][wave & 1] = s[nf];
    }
    __syncthreads();   // sRed ready; ALSO drains next-item kb0 staging

    if (tid < 128) {
      int anyBad = sBadW[0] | sBadW[1] | sBadW[2] | sBadW[3];
      float v = sRed[tid][0] + sRed[tid][1] + b1[k];
      if (anyBad == 0) v = fast_sigmoid(v);  // binary-input path
      out[(size_t)(n0 + tid) * D_TOW + k] = v;
    }
    // No extra barrier: next item's sRed write is separated from this
    // out-read by the next item's three barriers.
  }
}

extern "C" void kernel_launch(void* const* d_in, const int* in_sizes, int n_in,
                              void* d_out, int out_size, void* d_ws, size_t ws_size,
                              hipStream_t stream) {
  const float* x  = (const float*)d_in[0];
  const float* w0 = (const float*)d_in[1];
  const float* b0 = (const float*)d_in[2];
  const float* w1 = (const float*)d_in[3];
  const float* b1 = (const float*)d_in[4];
  float* out = (float*)d_out;

  char* ws = (char*)d_ws;
  int* flagArr = (int*)ws;                                   // 1 KB
  ushort* xb  = (ushort*)(ws + 4096);                        // 2 MB
  ushort* w0b = (ushort*)(ws + 4096 + N_SAMP * D_TOW * 2);   // 4 MB

  int total = (N_SAMP * D_TOW + D_TOW * D_HID * D_TOW) / 4;  // 786432 float4
  prep_kernel<<<total / 1024, 1024, 0, stream>>>(x, w0, xb, w0b, flagArr);

  towers_kernel<<<1024, 256, 0, stream>>>(xb, w0b, b0, w1, b1, flagArr, out);
}

// Round 6
// 202.907 us; speedup vs baseline: 2.2114x; 1.0002x over previous
//
#include <hip/hip_runtime.h>
#include <hip/hip_bf16.h>
#include <stdint.h>

#define N_SAMP 8192
#define D_TOW  128
#define D_HID  128

typedef __bf16 bf16x8 __attribute__((ext_vector_type(8)));
typedef float  f32x4  __attribute__((ext_vector_type(4)));
typedef float  f32x2  __attribute__((ext_vector_type(2)));

__device__ __forceinline__ ushort f2bf(float f) {
  union { float f; uint32_t u; } c; c.f = f;
  uint32_t u = c.u;
  return (ushort)((u + 0x7FFFu + ((u >> 16) & 1u)) >> 16);  // RNE
}

// sigmoid via raw HW ops: v_exp_f32 + v_rcp_f32.
__device__ __forceinline__ float fast_sigmoid(float p) {
  float e = __builtin_amdgcn_exp2f(p * -1.442695040888963f);
  return __builtin_amdgcn_rcpf(1.0f + e);
}

// fp32 -> bf16 convert. W0 is pre-scaled by -log2(e) so the towers MFMA
// directly produces exp2 arguments. x path writes a per-block "saw
// non-binary" flag UNCONDITIONALLY (no memset needed).
__global__ __launch_bounds__(1024) void prep_kernel(
    const float* __restrict__ x, const float* __restrict__ w0,
    ushort* __restrict__ xb, ushort* __restrict__ w0b,
    int* __restrict__ flagArr) {
  const int NX4 = (N_SAMP * D_TOW) / 4;  // 262144 -> x-blocks are bid 0..255
  int bid = blockIdx.x;
  int tid = threadIdx.x;
  int t = bid * 1024 + tid;
  if (bid < 256) {
    __shared__ int sbad;
    if (tid == 0) sbad = 0;
    float4 v = ((const float4*)x)[t];
    bool bad = !(((v.x == 0.f) || (v.x == 1.f)) &&
                 ((v.y == 0.f) || (v.y == 1.f)) &&
                 ((v.z == 0.f) || (v.z == 1.f)) &&
                 ((v.w == 0.f) || (v.w == 1.f)));
    ushort4 o;
    o.x = f2bf(v.x); o.y = f2bf(v.y); o.z = f2bf(v.z); o.w = f2bf(v.w);
    ((ushort4*)xb)[t] = o;
    __syncthreads();
    if (__ballot(bad) != 0ull && (tid & 63) == 0) sbad = 1;
    __syncthreads();
    if (tid == 0) flagArr[bid] = sbad;
  } else {
    const float c = -1.442695040888963f;
    int j = t - NX4;
    float4 v = ((const float4*)w0)[j];
    ushort4 o;
    o.x = f2bf(c * v.x); o.y = f2bf(c * v.y);
    o.z = f2bf(c * v.z); o.w = f2bf(c * v.w);
    ((ushort4*)w0b)[j] = o;
  }
}

__device__ __forceinline__ void g2l16(const void* g, void* l) {
  __builtin_amdgcn_global_load_lds(
      (const __attribute__((address_space(1))) void*)g,
      (__attribute__((address_space(3))) void*)l, 16, 0, 0);
}

// Stage one K-half (64 cols) of the X chunk and W0_k into LDS.
// LDS dest = uniform base + lane*16 (HW rule); XOR swizzle applied to the
// *global source* chunk: LDS[row][c] holds global chunk c^(row&7).
__device__ __forceinline__ void stage_half(
    const ushort* __restrict__ xg, const ushort* __restrict__ wg, int koff,
    ushort* sX, ushort* sW, int wave, int rowl, int slot) {
#pragma unroll
  for (int i = 0; i < 4; ++i) {
    int row = wave * 32 + i * 8 + rowl;
    int c = slot ^ (row & 7);
    int goff = row * 128 + koff + c * 8;
    int lbase = (wave * 32 + i * 8) * 128;
    g2l16(xg + goff, (char*)sX + lbase);
    g2l16(wg + goff, (char*)sW + lbase);
  }
}

// Two K=32 MFMA steps over the currently staged half.
__device__ __forceinline__ void mfma_half(
    const ushort* sW, const ushort* sX, const int* aBase, const int* bBase,
    int q, int cl, f32x4 acc[4][4]) {
#pragma unroll
  for (int t = 0; t < 2; ++t) {
    int ch = ((t * 4 + q) ^ (cl & 7)) << 4;   // swizzled 16B slot offset
    bf16x8 a[4], b[4];
#pragma unroll
    for (int hf = 0; hf < 4; ++hf)
      a[hf] = *(const bf16x8*)((const char*)sW + aBase[hf] + ch);
#pragma unroll
    for (int nf = 0; nf < 4; ++nf)
      b[nf] = *(const bf16x8*)((const char*)sX + bBase[nf] + ch);
    __builtin_amdgcn_s_setprio(1);
#pragma unroll
    for (int hf = 0; hf < 4; ++hf)
#pragma unroll
      for (int nf = 0; nf < 4; ++nf)
        acc[hf][nf] = __builtin_amdgcn_mfma_f32_16x16x32_bf16(
            a[hf], b[nf], acc[hf][nf], 0, 0, 0);
    __builtin_amdgcn_s_setprio(0);
  }
}

// PERSISTENT pipelined towers (R5 structure) with the write pathology fixed
// STRUCTURALLY: each block writes its 128-sample column to outT[k][n]
// (512 B contiguous, full 64 B sectors, no RFO) instead of scattered 4 B
// writes to out[n][k]. R5's 300 MB FETCH / 107 MB WRITE was RFO + partial-
// sector writeback + the resulting L2 pollution evicting X/W; with outT the
// per-XCD working set is provably <= W(512K)+X(2M) < 4 MB L2 regardless of
// block drift. A separate tiled transpose produces out[n][k].
// Grid 1024 = 4 blocks/CU; block owns tower k (W0_k L2-hot), iterates 8
// n-chunks; next item's kb0 stage issues before this item's trans-heavy
// epilogue (latency + barrier drain hide under ~1000 cyc of exp2/rcp).
__global__ __launch_bounds__(256, 4) void towers_kernel(
    const ushort* __restrict__ xb, const ushort* __restrict__ w0b,
    const float* __restrict__ b0, const float* __restrict__ w1,
    const float* __restrict__ b1, const int* __restrict__ flagArr,
    float* __restrict__ outT) {
  __shared__ __align__(16) ushort sX[128 * 64];  // 16 KB
  __shared__ __align__(16) ushort sW[128 * 64];  // 16 KB
  __shared__ float sRed[128][2];
  __shared__ int sBadW[4];

  int bid = blockIdx.x;          // 1024 blocks
  int xcd = bid & 7;
  int lb  = bid >> 3;            // 0..127 per XCD
  int k   = xcd * 16 + (lb & 15);
  int col = lb >> 4;             // 0..7

  int tid = threadIdx.x;
  int lane = tid & 63;
  int wave = tid >> 6;
  int q = lane >> 4;      // quad index (bits 4-5)
  int cl = lane & 15;
  int rowl = lane >> 3;   // 0..7 within a 1KB staging chunk
  int slot = lane & 7;

  const ushort* wg = w0b + k * (128 * 128);  // W0_k: [h][d] row-major bf16

  // Binary-flag OR-reduce (256 ints = 1 KB), once per block.
  int anyb = flagArr[tid];
  unsigned long long mb = __ballot(anyb != 0);
  if (lane == 0) sBadW[wave] = (mb != 0ull) ? 1 : 0;

  int R  = (wave >> 1) * 64;   // n-quadrant
  int Ch = (wave & 1) * 64;    // h-half

  // Row base byte-offsets (LDS row = 128 B), constant across items.
  int aBase[4], bBase[4];
#pragma unroll
  for (int f = 0; f < 4; ++f) {
    aBase[f] = (Ch + f * 16 + cl) * 128;     // W row = h
    bBase[f] = (R + f * 16 + cl) * 128;      // X row = n
  }

  const float cn = -1.442695040888963f;

  // Prologue: stage item 0, k-half 0.
  {
    const ushort* xg0 = xb + (size_t)col * (128 * 128);
    stage_half(xg0, wg, 0, sX, sW, wave, rowl, slot);
  }
  __syncthreads();   // compiler drains vmcnt -> item-0 kb0 visible

  for (int j = 0; j < 8; ++j) {
    int chunk = j * 8 + col;
    const ushort* xg = xb + (size_t)chunk * (128 * 128);
    int n0 = chunk * 128;

    // acc init = -log2e * b0 (bias folded into MFMA accumulator).
    // C layout: col = n = R + nf*16 + cl ; row = h = Ch + hf*16 + q*4 + r.
    f32x4 acc[4][4];             // [hf][nf]
#pragma unroll
    for (int hf = 0; hf < 4; ++hf) {
      int h = k * 128 + Ch + hf * 16 + q * 4;
      f32x4 bbs = *(const f32x4*)&b0[h] * cn;
#pragma unroll
      for (int nf = 0; nf < 4; ++nf)
        acc[hf][nf] = bbs;
    }

    mfma_half(sW, sX, aBase, bBase, q, cl, acc);   // K 0..63
    __syncthreads();                               // kb0 reads done
    stage_half(xg, wg, 64, sX, sW, wave, rowl, slot);
    __syncthreads();                               // kb1 visible (vmcnt drain)
    mfma_half(sW, sX, aBase, bBase, q, cl, acc);   // K 64..127
    __syncthreads();                               // kb1 reads done

    // Issue NEXT item's kb0 stage now; its latency + the barrier drain
    // hide under this item's trans-heavy epilogue.
    if (j < 7) {
      const ushort* xgn = xb + (size_t)(chunk + 8) * (128 * 128);
      stage_half(xgn, wg, 0, sX, sW, wave, rowl, slot);
    }

    // Epilogue: sigmoid = rcp(1 + exp2(acc)); rcps paired (1.5 trans/elem);
    // mul/fma paths paired as f32x2 for v_pk_*_f32.
    f32x2 s2[4] = {{0.f, 0.f}, {0.f, 0.f}, {0.f, 0.f}, {0.f, 0.f}};
#pragma unroll
    for (int hf = 0; hf < 4; ++hf) {
      int h = k * 128 + Ch + hf * 16 + q * 4;
      f32x4 wv = *(const f32x4*)&w1[h];
      f32x2 wa = {wv[0], wv[1]};
      f32x2 wb = {wv[2], wv[3]};
#pragma unroll
      for (int nf = 0; nf < 4; ++nf) {
        f32x4 qv = acc[hf][nf];
        f32x2 dA = {1.0f + __builtin_amdgcn_exp2f(qv[0]),
                    1.0f + __builtin_amdgcn_exp2f(qv[1])};
        f32x2 dB = {1.0f + __builtin_amdgcn_exp2f(qv[2]),
                    1.0f + __builtin_amdgcn_exp2f(qv[3])};
        float rA = __builtin_amdgcn_rcpf(dA[0] * dA[1]);
        float rB = __builtin_amdgcn_rcpf(dB[0] * dB[1]);
        f32x2 cA = (f32x2){dA[1], dA[0]} * (f32x2){rA, rA};
        f32x2 cB = (f32x2){dB[1], dB[0]} * (f32x2){rB, rB};
        s2[nf] += wa * cA;
        s2[nf] += wb * cB;
      }
    }
    float s[4];
#pragma unroll
    for (int nf = 0; nf < 4; ++nf)
      s[nf] = s2[nf][0] + s2[nf][1];

#pragma unroll
    for (int m = 16; m <= 32; m <<= 1)
#pragma unroll
      for (int nf = 0; nf < 4; ++nf)
        s[nf] += __shfl_xor(s[nf], m, 64);

    if (q == 0) {
#pragma unroll
      for (int nf = 0; nf < 4; ++nf)
        sRed[R + nf * 16 + cl][wave & 1] = s[nf];
    }
    __syncthreads();   // sRed ready; ALSO drains next-item kb0 staging

    if (tid < 128) {
      int anyBad = sBadW[0] | sBadW[1] | sBadW[2] | sBadW[3];
      float v = sRed[tid][0] + sRed[tid][1] + b1[k];
      if (anyBad == 0) v = fast_sigmoid(v);  // binary-input path
      // Transposed write: 128 consecutive floats = 512 B, full sectors,
      // timing-independent (no cross-block write-merge needed).
      outT[(size_t)k * N_SAMP + n0 + tid] = v;
    }
    // No extra barrier: next item's sRed write is separated from this
    // outT-read of sRed by the next item's three barriers.
  }
}

// Tiled transpose: out[n][k] = outT[k][n]. 128 blocks x 64-sample slabs.
// Loads are 256 B-contiguous per wave; stores are full 512 B rows; LDS
// padded to 129 floats/row -> conflict-free both directions.
__global__ __launch_bounds__(256) void transpose_kernel(
    const float* __restrict__ outT, float* __restrict__ out) {
  __shared__ float sT[64][129];
  int n0 = blockIdx.x * 64;
  int t = threadIdx.x;
#pragma unroll
  for (int i = 0; i < 32; ++i) {
    int idx = i * 256 + t;       // 0..8191
    int kk = idx >> 6;           // 0..127
    int nn = idx & 63;
    sT[nn][kk] = outT[(size_t)kk * N_SAMP + n0 + nn];
  }
  __syncthreads();
#pragma unroll
  for (int jj = 0; jj < 32; ++jj) {
    int idx = jj * 256 + t;
    int nn = idx >> 7;           // 0..63
    int kk = idx & 127;
    out[(size_t)(n0 + nn) * D_TOW + kk] = sT[nn][kk];
  }
}

extern "C" void kernel_launch(void* const* d_in, const int* in_sizes, int n_in,
                              void* d_out, int out_size, void* d_ws, size_t ws_size,
                              hipStream_t stream) {
  const float* x  = (const float*)d_in[0];
  const float* w0 = (const float*)d_in[1];
  const float* b0 = (const float*)d_in[2];
  const float* w1 = (const float*)d_in[3];
  const float* b1 = (const float*)d_in[4];
  float* out = (float*)d_out;

  char* ws = (char*)d_ws;
  int* flagArr = (int*)ws;                                   // 1 KB
  ushort* xb  = (ushort*)(ws + 4096);                        // 2 MB
  ushort* w0b = (ushort*)(ws + 4096 + N_SAMP * D_TOW * 2);   // 4 MB
  float* outT = (float*)(ws + 4096 + N_SAMP * D_TOW * 2
                               + D_TOW * D_HID * D_TOW * 2); // 4 MB

  int total = (N_SAMP * D_TOW + D_TOW * D_HID * D_TOW) / 4;  // 786432 float4
  prep_kernel<<<total / 1024, 1024, 0, stream>>>(x, w0, xb, w0b, flagArr);

  towers_kernel<<<1024, 256, 0, stream>>>(xb, w0b, b0, w1, b1, flagArr, outT);

  transpose_kernel<<<N_SAMP / 64, 256, 0, stream>>>(outT, out);
}

// Round 7
// 123.697 us; speedup vs baseline: 3.6275x; 1.6404x over previous
//
#include <hip/hip_runtime.h>
#include <hip/hip_bf16.h>
#include <stdint.h>

#define N_SAMP 8192
#define D_TOW  128
#define D_HID  128

typedef __bf16 bf16x8 __attribute__((ext_vector_type(8)));
typedef float  f32x4  __attribute__((ext_vector_type(4)));
typedef float  f32x2  __attribute__((ext_vector_type(2)));

#define WAIT_VM0() asm volatile("s_waitcnt vmcnt(0)" ::: "memory")
#define WAIT_VM4() asm volatile("s_waitcnt vmcnt(4)" ::: "memory")
#define WAIT_LGKM0() asm volatile("s_waitcnt lgkmcnt(0)" ::: "memory")
// raw barrier + compiler memory fence so loads can't hoist above it
#define BAR() do { __builtin_amdgcn_s_barrier(); \
                   asm volatile("" ::: "memory"); } while (0)

__device__ __forceinline__ ushort f2bf(float f) {
  union { float f; uint32_t u; } c; c.f = f;
  uint32_t u = c.u;
  return (ushort)((u + 0x7FFFu + ((u >> 16) & 1u)) >> 16);  // RNE
}

// sigmoid via raw HW ops: v_exp_f32 + v_rcp_f32.
__device__ __forceinline__ float fast_sigmoid(float p) {
  float e = __builtin_amdgcn_exp2f(p * -1.442695040888963f);
  return __builtin_amdgcn_rcpf(1.0f + e);
}

// fp32 -> bf16 convert. W0 is pre-scaled by -log2(e) so the towers MFMA
// directly produces exp2 arguments. x path writes a per-block "saw
// non-binary" flag UNCONDITIONALLY (no memset needed); flagArr = 256 ints.
__global__ __launch_bounds__(1024) void prep_kernel(
    const float* __restrict__ x, const float* __restrict__ w0,
    ushort* __restrict__ xb, ushort* __restrict__ w0b,
    int* __restrict__ flagArr) {
  const int NX4 = (N_SAMP * D_TOW) / 4;  // 262144 -> x-blocks are bid 0..255
  int bid = blockIdx.x;
  int tid = threadIdx.x;
  int t = bid * 1024 + tid;
  if (bid < 256) {
    __shared__ int sbad;
    if (tid == 0) sbad = 0;
    float4 v = ((const float4*)x)[t];
    bool bad = !(((v.x == 0.f) || (v.x == 1.f)) &&
                 ((v.y == 0.f) || (v.y == 1.f)) &&
                 ((v.z == 0.f) || (v.z == 1.f)) &&
                 ((v.w == 0.f) || (v.w == 1.f)));
    ushort4 o;
    o.x = f2bf(v.x); o.y = f2bf(v.y); o.z = f2bf(v.z); o.w = f2bf(v.w);
    ((ushort4*)xb)[t] = o;
    __syncthreads();
    if (__ballot(bad) != 0ull && (tid & 63) == 0) sbad = 1;
    __syncthreads();
    if (tid == 0) flagArr[bid] = sbad;
  } else {
    const float c = -1.442695040888963f;
    int j = t - NX4;
    float4 v = ((const float4*)w0)[j];
    ushort4 o;
    o.x = f2bf(c * v.x); o.y = f2bf(c * v.y);
    o.z = f2bf(c * v.z); o.w = f2bf(c * v.w);
    ((ushort4*)w0b)[j] = o;
  }
}

__device__ __forceinline__ void g2l16(const void* g, void* l) {
  __builtin_amdgcn_global_load_lds(
      (const __attribute__((address_space(1))) void*)g,
      (__attribute__((address_space(3))) void*)l, 16, 0, 0);
}

// Stage one K-QUARTER (32 cols) of X and W into LDS buffer `buf`.
// Quarter buffer layout: 128 rows x 64 B (4x16B slots). Slot d at row r
// holds global chunk s = ((d - ((r>>2)&3))&3) ^ (r&3)  [inverse of the
// read swizzle d(s,r) = ((s ^ (r&3)) + ((r>>2)&3))&3 -- a bijection that
// makes the 16-row frag reads exactly 2 lanes/bank = free].
// LDS dest = wave-uniform base + lane*16 (HW rule); swizzle applied to
// the *global source* address. 4 g2l16 per wave per quarter.
__device__ __forceinline__ void stage_q(
    const ushort* __restrict__ xg, const ushort* __restrict__ wg,
    int qq, int buf, ushort* sX, ushort* sW, int wave, int lane) {
#pragma unroll
  for (int i = 0; i < 2; ++i) {
    int r = i * 64 + wave * 16 + (lane >> 2);
    int dl = lane & 3;
    int s = ((dl - ((r >> 2) & 3)) & 3) ^ (r & 3);
    int goff = r * 128 + qq * 32 + s * 8;          // element offset
    int lb = buf * 8192 + (i * 64 + wave * 16) * 64;  // byte, wave-uniform
    g2l16(xg + goff, (char*)sX + lb);
    g2l16(wg + goff, (char*)sW + lb);
  }
}

// One block = one tower k x one 128-row chunk (R3 dispatch: grid 8192,
// k fast per XCD -> proven 10.6 MB FETCH / write-merge; persistent grids
// (R5/R6) showed an unexplained 290 MB L2-miss pathology -> abandoned).
// NEW vs R3: K split into 4 quarters, LDS double-buffered at 8 KB grain
// (total 33.5 KB unchanged, 4 blocks/CU), raw s_barrier + COUNTED
// s_waitcnt vmcnt(4) -- staging loads stay in flight across barriers
// (T3/T4 pattern), removing the two full vmcnt(0) drains of the 2-phase
// schedule (the ~72%-overhead structure per guide m233).
__global__ __launch_bounds__(256, 4) void towers_kernel(
    const ushort* __restrict__ xb, const ushort* __restrict__ w0b,
    const float* __restrict__ b0, const float* __restrict__ w1,
    const float* __restrict__ b1, const int* __restrict__ flagArr,
    float* __restrict__ out) {
  __shared__ __align__(16) ushort sX[2][128 * 32];  // 2 x 8 KB
  __shared__ __align__(16) ushort sW[2][128 * 32];  // 2 x 8 KB
  __shared__ float sRed[128][2];
  __shared__ int sBadW[4];

  int bid = blockIdx.x;          // 8192 blocks
  int xcd = bid & 7;
  int idx = bid >> 3;            // 0..1023 per XCD
  int k  = xcd * 16 + (idx & 15);
  int n0 = (idx >> 4) * 128;

  int tid = threadIdx.x;
  int lane = tid & 63;
  int wave = tid >> 6;
  int q = lane >> 4;      // quad index (bits 4-5)
  int cl = lane & 15;

  const ushort* xg = xb + (size_t)n0 * 128;  // [128][128] row-major bf16
  const ushort* wg = w0b + k * (128 * 128);  // W0_k: [h][d] row-major bf16

  // ---- prologue vmem (flag, b0, w1), fully drained before staging so the
  // counted vmcnt waits below track ONLY staging ops ----
  int anyb = flagArr[tid];
  unsigned long long mb = __ballot(anyb != 0);
  if (lane == 0) sBadW[wave] = (mb != 0ull) ? 1 : 0;

  int R  = (wave >> 1) * 64;   // n-quadrant
  int Ch = (wave & 1) * 64;    // h-half

  // acc init = -log2e * b0 (bias folded into MFMA accumulator).
  // C layout: col = n = R + nf*16 + cl ; row = h = Ch + hf*16 + q*4 + r.
  const float cn = -1.442695040888963f;
  f32x4 acc[4][4];             // [hf][nf]
  f32x4 wv[4];
#pragma unroll
  for (int hf = 0; hf < 4; ++hf) {
    int h = k * 128 + Ch + hf * 16 + q * 4;
    f32x4 bbs = *(const f32x4*)&b0[h] * cn;
    wv[hf] = *(const f32x4*)&w1[h];
#pragma unroll
    for (int nf = 0; nf < 4; ++nf)
      acc[hf][nf] = bbs;
  }

  // Frag byte-offsets within an 8 KB quarter buffer (row = 64 B).
  // Lane-constant slot: d = ((q ^ (cl&3)) + ((cl>>2)&3)) & 3.
  int dl = ((q ^ (cl & 3)) + ((cl >> 2) & 3)) & 3;
  int aOff[4], bOff[4];
#pragma unroll
  for (int f = 0; f < 4; ++f) {
    aOff[f] = (Ch + f * 16 + cl) * 64 + dl * 16;   // W row = h
    bOff[f] = (R + f * 16 + cl) * 64 + dl * 16;    // X row = n
  }

  WAIT_VM0();   // drain flag/b0/w1 -> staging counts exact from here

  stage_q(xg, wg, 0, 0, &sX[0][0], &sW[0][0], wave, lane);  // out = 4
  stage_q(xg, wg, 1, 1, &sX[0][0], &sW[0][0], wave, lane);  // out = 8
  WAIT_VM4();   // q0's 4 oldest complete (per wave)
  BAR();        // -> complete across all waves

#pragma unroll
  for (int qq = 0; qq < 4; ++qq) {
    const char* bx = (const char*)&sX[0][0] + (qq & 1) * 8192;
    const char* bw = (const char*)&sW[0][0] + (qq & 1) * 8192;
    bf16x8 a[4], b[4];
#pragma unroll
    for (int f = 0; f < 4; ++f) {
      a[f] = *(const bf16x8*)(bw + aOff[f]);
      b[f] = *(const bf16x8*)(bx + bOff[f]);
    }
    if (qq < 2) {
      WAIT_LGKM0();   // my frag reads of this buffer complete
      BAR();          // all waves' reads complete -> safe to overwrite
      stage_q(xg, wg, qq + 2, qq & 1, &sX[0][0], &sW[0][0], wave, lane);
    }
    __builtin_amdgcn_s_setprio(1);
#pragma unroll
    for (int hf = 0; hf < 4; ++hf)
#pragma unroll
      for (int nf = 0; nf < 4; ++nf)
        acc[hf][nf] = __builtin_amdgcn_mfma_f32_16x16x32_bf16(
            a[hf], b[nf], acc[hf][nf], 0, 0, 0);
    __builtin_amdgcn_s_setprio(0);
    if (qq < 3) {
      if (qq == 2) { WAIT_VM0(); }  // q3 complete
      else        { WAIT_VM4(); }   // q(qq+1) complete, q(qq+2) in flight
      BAR();
    }
  }

  // Epilogue: sigmoid = rcp(1 + exp2(acc)); rcps paired (1.5 trans/elem);
  // mul/fma paths paired as f32x2 for v_pk_*_f32.
  f32x2 s2[4] = {{0.f, 0.f}, {0.f, 0.f}, {0.f, 0.f}, {0.f, 0.f}};
#pragma unroll
  for (int hf = 0; hf < 4; ++hf) {
    f32x2 wa = {wv[hf][0], wv[hf][1]};
    f32x2 wb = {wv[hf][2], wv[hf][3]};
#pragma unroll
    for (int nf = 0; nf < 4; ++nf) {
      f32x4 qv = acc[hf][nf];
      f32x2 dA = {1.0f + __builtin_amdgcn_exp2f(qv[0]),
                  1.0f + __builtin_amdgcn_exp2f(qv[1])};
      f32x2 dB = {1.0f + __builtin_amdgcn_exp2f(qv[2]),
                  1.0f + __builtin_amdgcn_exp2f(qv[3])};
      float rA = __builtin_amdgcn_rcpf(dA[0] * dA[1]);
      float rB = __builtin_amdgcn_rcpf(dB[0] * dB[1]);
      f32x2 cA = (f32x2){dA[1], dA[0]} * (f32x2){rA, rA};
      f32x2 cB = (f32x2){dB[1], dB[0]} * (f32x2){rB, rB};
      s2[nf] += wa * cA;
      s2[nf] += wb * cB;
    }
  }
  float s[4];
#pragma unroll
  for (int nf = 0; nf < 4; ++nf)
    s[nf] = s2[nf][0] + s2[nf][1];

#pragma unroll
  for (int m = 16; m <= 32; m <<= 1)
#pragma unroll
    for (int nf = 0; nf < 4; ++nf)
      s[nf] += __shfl_xor(s[nf], m, 64);

  if (q == 0) {
#pragma unroll
    for (int nf = 0; nf < 4; ++nf)
      sRed[R + nf * 16 + cl][wave & 1] = s[nf];
  }
  __syncthreads();   // full drain fine here: no staging in flight

  if (tid < 128) {
    int anyBad = sBadW[0] | sBadW[1] | sBadW[2] | sBadW[3];
    float v = sRed[tid][0] + sRed[tid][1] + b1[k];
    if (anyBad == 0) v = fast_sigmoid(v);  // binary-input path
    out[(size_t)(n0 + tid) * D_TOW + k] = v;
  }
}

extern "C" void kernel_launch(void* const* d_in, const int* in_sizes, int n_in,
                              void* d_out, int out_size, void* d_ws, size_t ws_size,
                              hipStream_t stream) {
  const float* x  = (const float*)d_in[0];
  const float* w0 = (const float*)d_in[1];
  const float* b0 = (const float*)d_in[2];
  const float* w1 = (const float*)d_in[3];
  const float* b1 = (const float*)d_in[4];
  float* out = (float*)d_out;

  char* ws = (char*)d_ws;
  int* flagArr = (int*)ws;                                   // 1 KB
  ushort* xb  = (ushort*)(ws + 4096);                        // 2 MB
  ushort* w0b = (ushort*)(ws + 4096 + N_SAMP * D_TOW * 2);   // 4 MB

  int total = (N_SAMP * D_TOW + D_TOW * D_HID * D_TOW) / 4;  // 786432 float4
  prep_kernel<<<total / 1024, 1024, 0, stream>>>(x, w0, xb, w0b, flagArr);

  towers_kernel<<<8192, 256, 0, stream>>>(xb, w0b, b0, w1, b1, flagArr, out);
}

// Round 8
// 122.865 us; speedup vs baseline: 3.6521x; 1.0068x over previous
//
#include <hip/hip_runtime.h>
#include <hip/hip_bf16.h>
#include <stdint.h>

#define N_SAMP 8192
#define D_TOW  128
#define D_HID  128

typedef __bf16 bf16x8 __attribute__((ext_vector_type(8)));
typedef float  f32x4  __attribute__((ext_vector_type(4)));
typedef float  f32x2  __attribute__((ext_vector_type(2)));

__device__ __forceinline__ ushort f2bf(float f) {
  union { float f; uint32_t u; } c; c.f = f;
  uint32_t u = c.u;
  return (ushort)((u + 0x7FFFu + ((u >> 16) & 1u)) >> 16);  // RNE
}

// sigmoid via raw HW ops: v_exp_f32 + v_rcp_f32.
__device__ __forceinline__ float fast_sigmoid(float p) {
  float e = __builtin_amdgcn_exp2f(p * -1.442695040888963f);
  return __builtin_amdgcn_rcpf(1.0f + e);
}

// fp32 -> bf16 convert. W0 is pre-scaled by -log2(e) so the towers MFMA
// directly produces exp2 arguments. x path writes a per-block "saw
// non-binary" flag UNCONDITIONALLY (no memset needed); flagArr = 256 ints.
__global__ __launch_bounds__(1024) void prep_kernel(
    const float* __restrict__ x, const float* __restrict__ w0,
    ushort* __restrict__ xb, ushort* __restrict__ w0b,
    int* __restrict__ flagArr) {
  const int NX4 = (N_SAMP * D_TOW) / 4;  // 262144 -> x-blocks are bid 0..255
  int bid = blockIdx.x;
  int tid = threadIdx.x;
  int t = bid * 1024 + tid;
  if (bid < 256) {
    __shared__ int sbad;
    if (tid == 0) sbad = 0;
    float4 v = ((const float4*)x)[t];
    bool bad = !(((v.x == 0.f) || (v.x == 1.f)) &&
                 ((v.y == 0.f) || (v.y == 1.f)) &&
                 ((v.z == 0.f) || (v.z == 1.f)) &&
                 ((v.w == 0.f) || (v.w == 1.f)));
    ushort4 o;
    o.x = f2bf(v.x); o.y = f2bf(v.y); o.z = f2bf(v.z); o.w = f2bf(v.w);
    ((ushort4*)xb)[t] = o;
    __syncthreads();
    if (__ballot(bad) != 0ull && (tid & 63) == 0) sbad = 1;
    __syncthreads();
    if (tid == 0) flagArr[bid] = sbad;
  } else {
    const float c = -1.442695040888963f;
    int j = t - NX4;
    float4 v = ((const float4*)w0)[j];
    ushort4 o;
    o.x = f2bf(c * v.x); o.y = f2bf(c * v.y);
    o.z = f2bf(c * v.z); o.w = f2bf(c * v.w);
    ((ushort4*)w0b)[j] = o;
  }
}

__device__ __forceinline__ void g2l16(const void* g, void* l) {
  __builtin_amdgcn_global_load_lds(
      (const __attribute__((address_space(1))) void*)g,
      (__attribute__((address_space(3))) void*)l, 16, 0, 0);
}

// One block = one tower k x one 256-row chunk of samples. 512 threads,
// 8 waves (4 n-quadrants x 2 h-halves); per-wave tile/code IDENTICAL to
// the proven 57.7us R3 kernel (64 VGPR + 64 AGPR = 128 = the (*,4) cap).
// R4's regression was ONLY __launch_bounds__(512,6) capping regs at 85 ->
// acc spill -> 640 MB scratch traffic; (512,4) removes that while keeping
// the geometry win: W0_k staged once per 256 samples -> total DMA volume
// 512->384 MB (-25% on L2-fetch and LDS-write terms of the R3 budget).
// LDS rows are 64 bf16 (8x16B slots); slot holds global chunk slot^(row&7)
// -> conflict-free ds_read_b128 (R3-proven, 0 conflicts; R7's 64B-row
// variant measured 4.2M conflict cycles -> dropped).
// Block mapping: per XCD, k is the FAST index -> 16 towers sharing an
// n-chunk run concurrently -> out[n][k0..k0+15] write-merges in L2
// (streaming dispatch only: persistent grids R5/R6 showed a 290 MB
// L2-miss pathology and are abandoned).
__global__ __launch_bounds__(512, 4) void towers_kernel(
    const ushort* __restrict__ xb, const ushort* __restrict__ w0b,
    const float* __restrict__ b0, const float* __restrict__ w1,
    const float* __restrict__ b1, const int* __restrict__ flagArr,
    float* __restrict__ out) {
  __shared__ __align__(16) ushort sX[256 * 64];  // 32 KB
  __shared__ __align__(16) ushort sW[128 * 64];  // 16 KB
  __shared__ float sRed[256][2];                 // 2 KB
  __shared__ int sBadW[8];

  int bid = blockIdx.x;          // 4096 blocks
  int xcd = bid & 7;
  int idx = bid >> 3;            // 0..511 per XCD
  int k  = xcd * 16 + (idx & 15);
  int n0 = (idx >> 4) * 256;

  int tid = threadIdx.x;
  int lane = tid & 63;
  int wave = tid >> 6;           // 0..7
  int q = lane >> 4;             // quad index (bits 4-5)
  int cl = lane & 15;
  int rowl = lane >> 3;          // 0..7 within a 1KB staging chunk
  int slot = lane & 7;

  const ushort* xg = xb + (size_t)n0 * 128;  // [256][128] row-major bf16
  const ushort* wg = w0b + k * (128 * 128);  // W0_k: [h][d] row-major bf16

  // Phase-0 staging issued first so latency hides under flag read +
  // bias load + acc init. X: 4 issues/wave (rows wave*32..+31);
  // W: 2 issues/wave (rows wave*16..+15).
#pragma unroll
  for (int i = 0; i < 4; ++i) {
    int row = wave * 32 + i * 8 + rowl;
    int c = slot ^ (row & 7);
    g2l16(xg + row * 128 + c * 8, (char*)sX + (wave * 32 + i * 8) * 128);
  }
#pragma unroll
  for (int i = 0; i < 2; ++i) {
    int row = wave * 16 + i * 8 + rowl;
    int c = slot ^ (row & 7);
    g2l16(wg + row * 128 + c * 8, (char*)sW + (wave * 16 + i * 8) * 128);
  }

  // Binary-flag OR-reduce (256 ints; waves 4..7 re-read 0..255 harmlessly).
  int anyb = flagArr[tid & 255];
  unsigned long long mb = __ballot(anyb != 0);
  if (lane == 0) sBadW[wave] = (mb != 0ull) ? 1 : 0;

  int R  = (wave >> 1) * 64;   // n-quadrant (0..3)
  int Ch = (wave & 1) * 64;    // h-half

  // acc init = -log2e * b0 (bias folded into MFMA accumulator).
  // C layout: col = n = R + nf*16 + cl ; row = h = Ch + hf*16 + q*4 + r.
  const float cn = -1.442695040888963f;
  f32x4 acc[4][4];             // [hf][nf]
#pragma unroll
  for (int hf = 0; hf < 4; ++hf) {
    int h = k * 128 + Ch + hf * 16 + q * 4;
    f32x4 bbs = *(const f32x4*)&b0[h] * cn;
#pragma unroll
    for (int nf = 0; nf < 4; ++nf)
      acc[hf][nf] = bbs;
  }

  // Row base byte-offsets (LDS row = 128 B).
  int aBase[4], bBase[4];
#pragma unroll
  for (int f = 0; f < 4; ++f) {
    aBase[f] = (Ch + f * 16 + cl) * 128;     // W row = h   (sW: 128 rows)
    bBase[f] = (R + f * 16 + cl) * 128;      // X row = n   (sX: 256 rows)
  }

#pragma unroll
  for (int kb = 0; kb < 2; ++kb) {
    __syncthreads();   // staged data visible (compiler drains vmcnt first)

#pragma unroll
    for (int t = 0; t < 2; ++t) {  // 2 x K=32 per phase
      int ch = ((t * 4 + q) ^ (cl & 7)) << 4;   // swizzled 16B slot offset
      bf16x8 a[4], b[4];
#pragma unroll
      for (int hf = 0; hf < 4; ++hf)
        a[hf] = *(const bf16x8*)((const char*)sW + aBase[hf] + ch);
#pragma unroll
      for (int nf = 0; nf < 4; ++nf)
        b[nf] = *(const bf16x8*)((const char*)sX + bBase[nf] + ch);
      __builtin_amdgcn_s_setprio(1);
#pragma unroll
      for (int hf = 0; hf < 4; ++hf)
#pragma unroll
        for (int nf = 0; nf < 4; ++nf)
          acc[hf][nf] = __builtin_amdgcn_mfma_f32_16x16x32_bf16(
              a[hf], b[nf], acc[hf][nf], 0, 0, 0);
      __builtin_amdgcn_s_setprio(0);
    }

    if (kb == 0) {
      __syncthreads();   // everyone done reading phase-0 LDS
      // Stage the second k-half [64..127] of both tiles.
#pragma unroll
      for (int i = 0; i < 4; ++i) {
        int row = wave * 32 + i * 8 + rowl;
        int c = slot ^ (row & 7);
        g2l16(xg + row * 128 + 64 + c * 8,
              (char*)sX + (wave * 32 + i * 8) * 128);
      }
#pragma unroll
      for (int i = 0; i < 2; ++i) {
        int row = wave * 16 + i * 8 + rowl;
        int c = slot ^ (row & 7);
        g2l16(wg + row * 128 + 64 + c * 8,
              (char*)sW + (wave * 16 + i * 8) * 128);
      }
    }
  }

  // Epilogue: sigmoid = rcp(1 + exp2(acc)); rcps paired (1.5 trans/elem);
  // mul/fma paths paired as f32x2 for v_pk_*_f32. w1 loaded HERE (not
  // hoisted) to keep arch VGPR at 64 under the 128 cap.
  f32x2 s2[4] = {{0.f, 0.f}, {0.f, 0.f}, {0.f, 0.f}, {0.f, 0.f}};
#pragma unroll
  for (int hf = 0; hf < 4; ++hf) {
    int h = k * 128 + Ch + hf * 16 + q * 4;
    f32x4 wv = *(const f32x4*)&w1[h];
    f32x2 wa = {wv[0], wv[1]};
    f32x2 wb = {wv[2], wv[3]};
#pragma unroll
    for (int nf = 0; nf < 4; ++nf) {
      f32x4 qv = acc[hf][nf];
      f32x2 dA = {1.0f + __builtin_amdgcn_exp2f(qv[0]),
                  1.0f + __builtin_amdgcn_exp2f(qv[1])};
      f32x2 dB = {1.0f + __builtin_amdgcn_exp2f(qv[2]),
                  1.0f + __builtin_amdgcn_exp2f(qv[3])};
      float rA = __builtin_amdgcn_rcpf(dA[0] * dA[1]);
      float rB = __builtin_amdgcn_rcpf(dB[0] * dB[1]);
      f32x2 cA = (f32x2){dA[1], dA[0]} * (f32x2){rA, rA};
      f32x2 cB = (f32x2){dB[1], dB[0]} * (f32x2){rB, rB};
      s2[nf] += wa * cA;
      s2[nf] += wb * cB;
    }
  }
  float s[4];
#pragma unroll
  for (int nf = 0; nf < 4; ++nf)
    s[nf] = s2[nf][0] + s2[nf][1];

#pragma unroll
  for (int m = 16; m <= 32; m <<= 1)
#pragma unroll
    for (int nf = 0; nf < 4; ++nf)
      s[nf] += __shfl_xor(s[nf], m, 64);

  if (q == 0) {
#pragma unroll
    for (int nf = 0; nf < 4; ++nf)
      sRed[R + nf * 16 + cl][wave & 1] = s[nf];
  }
  __syncthreads();

  if (tid < 256) {
    int anyBad = sBadW[0] | sBadW[1] | sBadW[2] | sBadW[3] |
                 sBadW[4] | sBadW[5] | sBadW[6] | sBadW[7];
    float v = sRed[tid][0] + sRed[tid][1] + b1[k];
    if (anyBad == 0) v = fast_sigmoid(v);  // binary-input path
    out[(size_t)(n0 + tid) * D_TOW + k] = v;
  }
}

extern "C" void kernel_launch(void* const* d_in, const int* in_sizes, int n_in,
                              void* d_out, int out_size, void* d_ws, size_t ws_size,
                              hipStream_t stream) {
  const float* x  = (const float*)d_in[0];
  const float* w0 = (const float*)d_in[1];
  const float* b0 = (const float*)d_in[2];
  const float* w1 = (const float*)d_in[3];
  const float* b1 = (const float*)d_in[4];
  float* out = (float*)d_out;

  char* ws = (char*)d_ws;
  int* flagArr = (int*)ws;                                   // 1 KB
  ushort* xb  = (ushort*)(ws + 4096);                        // 2 MB
  ushort* w0b = (ushort*)(ws + 4096 + N_SAMP * D_TOW * 2);   // 4 MB

  int total = (N_SAMP * D_TOW + D_TOW * D_HID * D_TOW) / 4;  // 786432 float4
  prep_kernel<<<total / 1024, 1024, 0, stream>>>(x, w0, xb, w0b, flagArr);

  towers_kernel<<<4096, 512, 0, stream>>>(xb, w0b, b0, w1, b1, flagArr, out);
}

// Round 9
// 122.711 us; speedup vs baseline: 3.6567x; 1.0013x over previous
//
#include <hip/hip_runtime.h>
#include <hip/hip_bf16.h>
#include <stdint.h>

#define N_SAMP 8192
#define D_TOW  128
#define D_HID  128

typedef __bf16 bf16x8 __attribute__((ext_vector_type(8)));
typedef float  f32x4  __attribute__((ext_vector_type(4)));
typedef float  f32x2  __attribute__((ext_vector_type(2)));

__device__ __forceinline__ ushort f2bf(float f) {
  union { float f; uint32_t u; } c; c.f = f;
  uint32_t u = c.u;
  return (ushort)((u + 0x7FFFu + ((u >> 16) & 1u)) >> 16);  // RNE
}

// sigmoid via raw HW ops: v_exp_f32 + v_rcp_f32.
__device__ __forceinline__ float fast_sigmoid(float p) {
  float e = __builtin_amdgcn_exp2f(p * -1.442695040888963f);
  return __builtin_amdgcn_rcpf(1.0f + e);
}

// fp32 -> bf16 convert. W0 is pre-scaled by -log2(e) so the towers MFMA
// directly produces exp2 arguments. x path writes a per-block "saw
// non-binary" flag UNCONDITIONALLY (no memset needed); flagArr = 256 ints.
__global__ __launch_bounds__(1024) void prep_kernel(
    const float* __restrict__ x, const float* __restrict__ w0,
    ushort* __restrict__ xb, ushort* __restrict__ w0b,
    int* __restrict__ flagArr) {
  const int NX4 = (N_SAMP * D_TOW) / 4;  // 262144 -> x-blocks are bid 0..255
  int bid = blockIdx.x;
  int tid = threadIdx.x;
  int t = bid * 1024 + tid;
  if (bid < 256) {
    __shared__ int sbad;
    if (tid == 0) sbad = 0;
    float4 v = ((const float4*)x)[t];
    bool bad = !(((v.x == 0.f) || (v.x == 1.f)) &&
                 ((v.y == 0.f) || (v.y == 1.f)) &&
                 ((v.z == 0.f) || (v.z == 1.f)) &&
                 ((v.w == 0.f) || (v.w == 1.f)));
    ushort4 o;
    o.x = f2bf(v.x); o.y = f2bf(v.y); o.z = f2bf(v.z); o.w = f2bf(v.w);
    ((ushort4*)xb)[t] = o;
    __syncthreads();
    if (__ballot(bad) != 0ull && (tid & 63) == 0) sbad = 1;
    __syncthreads();
    if (tid == 0) flagArr[bid] = sbad;
  } else {
    const float c = -1.442695040888963f;
    int j = t - NX4;
    float4 v = ((const float4*)w0)[j];
    ushort4 o;
    o.x = f2bf(c * v.x); o.y = f2bf(c * v.y);
    o.z = f2bf(c * v.z); o.w = f2bf(c * v.w);
    ((ushort4*)w0b)[j] = o;
  }
}

__device__ __forceinline__ void g2l16(const void* g, void* l) {
  __builtin_amdgcn_global_load_lds(
      (const __attribute__((address_space(1))) void*)g,
      (__attribute__((address_space(3))) void*)l, 16, 0, 0);
}

// EXACT R3 structure (best measured: towers 57.7us, e2e 119.9us) + ONE new
// mechanism: phase-staggering. R3's counters show no pipe >50% busy and
// 4 independent blocks/CU, yet component-sum ~= wall clock: co-resident
// blocks are PHASE-LOCKED (same launch instant, same durations), so all
// waves on a SIMD stall on stage-wait/barriers simultaneously. A 0..3072
// cycle start offset (keyed so same-CU blocks differ under either plausible
// block->CU adjacency) lets one block's MFMA/epilogue cover another's
// stage-wait. Sleep yields issue slots, so cost is only the tail (~1us).
// All other R3 decisions retained: 2-phase K-split (33.5 KB LDS, 4 blk/CU,
// 64 VGPR + 64 AGPR = the (256,4) cap), 8-slot XOR swizzle (0 conflicts),
// k-fast XCD mapping (write-merge, 10.3 MB FETCH), bias-folded acc init,
// paired-rcp f32x2 epilogue. Persistent grids (R5/R6), counted-vmcnt
// pipelining (R7), and 512-thr geometry (R4/R8) all measured worse.
__global__ __launch_bounds__(256, 4) void towers_kernel(
    const ushort* __restrict__ xb, const ushort* __restrict__ w0b,
    const float* __restrict__ b0, const float* __restrict__ w1,
    const float* __restrict__ b1, const int* __restrict__ flagArr,
    float* __restrict__ out) {
  __shared__ __align__(16) ushort sX[128 * 64];  // 16 KB
  __shared__ __align__(16) ushort sW[128 * 64];  // 16 KB
  __shared__ float sRed[128][2];
  __shared__ int sBadW[4];

  int bid = blockIdx.x;
  int xcd = bid & 7;
  int idx = bid >> 3;            // 0..1023 per XCD
  int k  = xcd * 16 + (idx & 15);
  int n0 = (idx >> 4) * 128;

  // Phase stagger: 0/1024/2048/3072 cycles. ph differs among co-resident
  // blocks whether same-CU neighbors are consecutive idx or idx+32 apart.
  int ph = ((idx >> 5) ^ idx) & 3;
  if (ph & 1) __builtin_amdgcn_s_sleep(16);
  if (ph & 2) { __builtin_amdgcn_s_sleep(16); __builtin_amdgcn_s_sleep(16); }

  int tid = threadIdx.x;
  int lane = tid & 63;
  int wave = tid >> 6;
  int q = lane >> 4;      // quad index (bits 4-5)
  int cl = lane & 15;

  const ushort* xg = xb + (size_t)n0 * 128;  // [128][128] row-major bf16
  const ushort* wg = w0b + k * (128 * 128);  // W0_k: [h][d] row-major bf16

  int R  = (wave >> 1) * 64;   // n-quadrant
  int Ch = (wave & 1) * 64;    // h-half

  int rowl = lane >> 3;   // 0..7 within a 1KB staging chunk
  int slot = lane & 7;

  // Issue phase-0 staging first so the latency hides under flag read +
  // bias load + acc init. LDS dest = uniform base + lane*16 (HW rule);
  // XOR swizzle applied to the *global source* chunk: LDS[row][c] holds
  // global chunk c^(row&7) -> conflict-free ds_read_b128 (measured 0).
#pragma unroll
  for (int i = 0; i < 4; ++i) {
    int row = wave * 32 + i * 8 + rowl;
    int c = slot ^ (row & 7);
    int goff = row * 128 + c * 8;
    int lbase = (wave * 32 + i * 8) * 128;
    g2l16(xg + goff, (char*)sX + lbase);
    g2l16(wg + goff, (char*)sW + lbase);
  }

  // Binary-flag OR-reduce (256 ints = 1 KB).
  int anyb = flagArr[tid];
  unsigned long long mb = __ballot(anyb != 0);
  if (lane == 0) sBadW[wave] = (mb != 0ull) ? 1 : 0;

  // acc init = -log2e * b0 (bias folded into MFMA accumulator).
  // C layout: col = n = R + nf*16 + cl ; row = h = Ch + hf*16 + q*4 + r.
  const float cn = -1.442695040888963f;
  f32x4 acc[4][4];             // [hf][nf]
#pragma unroll
  for (int hf = 0; hf < 4; ++hf) {
    int h = k * 128 + Ch + hf * 16 + q * 4;
    f32x4 bbs = *(const f32x4*)&b0[h] * cn;
#pragma unroll
    for (int nf = 0; nf < 4; ++nf)
      acc[hf][nf] = bbs;
  }

  // Row base byte-offsets (LDS row = 128 B).
  int aBase[4], bBase[4];
#pragma unroll
  for (int f = 0; f < 4; ++f) {
    aBase[f] = (Ch + f * 16 + cl) * 128;     // W row = h
    bBase[f] = (R + f * 16 + cl) * 128;      // X row = n
  }

#pragma unroll
  for (int kb = 0; kb < 2; ++kb) {
    __syncthreads();   // staged data visible (compiler drains vmcnt first)

#pragma unroll
    for (int t = 0; t < 2; ++t) {  // 2 x K=32 per phase
      int ch = ((t * 4 + q) ^ (cl & 7)) << 4;   // swizzled 16B slot offset
      bf16x8 a[4], b[4];
#pragma unroll
      for (int hf = 0; hf < 4; ++hf)
        a[hf] = *(const bf16x8*)((const char*)sW + aBase[hf] + ch);
#pragma unroll
      for (int nf = 0; nf < 4; ++nf)
        b[nf] = *(const bf16x8*)((const char*)sX + bBase[nf] + ch);
      __builtin_amdgcn_s_setprio(1);
#pragma unroll
      for (int hf = 0; hf < 4; ++hf)
#pragma unroll
        for (int nf = 0; nf < 4; ++nf)
          acc[hf][nf] = __builtin_amdgcn_mfma_f32_16x16x32_bf16(
              a[hf], b[nf], acc[hf][nf], 0, 0, 0);
      __builtin_amdgcn_s_setprio(0);
    }

    if (kb == 0) {
      __syncthreads();   // everyone done reading phase-0 LDS
      // Stage the second k-half [64..127] of both tiles.
#pragma unroll
      for (int i = 0; i < 4; ++i) {
        int row = wave * 32 + i * 8 + rowl;
        int c = slot ^ (row & 7);
        int goff = row * 128 + 64 + c * 8;
        int lbase = (wave * 32 + i * 8) * 128;
        g2l16(xg + goff, (char*)sX + lbase);
        g2l16(wg + goff, (char*)sW + lbase);
      }
    }
  }

  // Epilogue: sigmoid = rcp(1 + exp2(acc)); rcps paired (1.5 trans/elem);
  // mul/fma paths paired as f32x2 for v_pk_*_f32. w1 loaded here (not
  // hoisted) to keep arch VGPR at 64 under the 128-reg cap.
  f32x2 s2[4] = {{0.f, 0.f}, {0.f, 0.f}, {0.f, 0.f}, {0.f, 0.f}};
#pragma unroll
  for (int hf = 0; hf < 4; ++hf) {
    int h = k * 128 + Ch + hf * 16 + q * 4;
    f32x4 wv = *(const f32x4*)&w1[h];
    f32x2 wa = {wv[0], wv[1]};
    f32x2 wb = {wv[2], wv[3]};
#pragma unroll
    for (int nf = 0; nf < 4; ++nf) {
      f32x4 qv = acc[hf][nf];
      f32x2 dA = {1.0f + __builtin_amdgcn_exp2f(qv[0]),
                  1.0f + __builtin_amdgcn_exp2f(qv[1])};
      f32x2 dB = {1.0f + __builtin_amdgcn_exp2f(qv[2]),
                  1.0f + __builtin_amdgcn_exp2f(qv[3])};
      float rA = __builtin_amdgcn_rcpf(dA[0] * dA[1]);
      float rB = __builtin_amdgcn_rcpf(dB[0] * dB[1]);
      f32x2 cA = (f32x2){dA[1], dA[0]} * (f32x2){rA, rA};
      f32x2 cB = (f32x2){dB[1], dB[0]} * (f32x2){rB, rB};
      s2[nf] += wa * cA;
      s2[nf] += wb * cB;
    }
  }
  float s[4];
#pragma unroll
  for (int nf = 0; nf < 4; ++nf)
    s[nf] = s2[nf][0] + s2[nf][1];

#pragma unroll
  for (int m = 16; m <= 32; m <<= 1)
#pragma unroll
    for (int nf = 0; nf < 4; ++nf)
      s[nf] += __shfl_xor(s[nf], m, 64);

  if (q == 0) {
#pragma unroll
    for (int nf = 0; nf < 4; ++nf)
      sRed[R + nf * 16 + cl][wave & 1] = s[nf];
  }
  __syncthreads();

  if (tid < 128) {
    int anyBad = sBadW[0] | sBadW[1] | sBadW[2] | sBadW[3];
    float v = sRed[tid][0] + sRed[tid][1] + b1[k];
    if (anyBad == 0) v = fast_sigmoid(v);  // binary-input path
    out[(size_t)(n0 + tid) * D_TOW + k] = v;
  }
}

extern "C" void kernel_launch(void* const* d_in, const int* in_sizes, int n_in,
                              void* d_out, int out_size, void* d_ws, size_t ws_size,
                              hipStream_t stream) {
  const float* x  = (const float*)d_in[0];
  const float* w0 = (const float*)d_in[1];
  const float* b0 = (const float*)d_in[2];
  const float* w1 = (const float*)d_in[3];
  const float* b1 = (const float*)d_in[4];
  float* out = (float*)d_out;

  char* ws = (char*)d_ws;
  int* flagArr = (int*)ws;                                   // 1 KB
  ushort* xb  = (ushort*)(ws + 4096);                        // 2 MB
  ushort* w0b = (ushort*)(ws + 4096 + N_SAMP * D_TOW * 2);   // 4 MB

  int total = (N_SAMP * D_TOW + D_TOW * D_HID * D_TOW) / 4;  // 786432 float4
  prep_kernel<<<total / 1024, 1024, 0, stream>>>(x, w0, xb, w0b, flagArr);

  towers_kernel<<<8192, 256, 0, stream>>>(xb, w0b, b0, w1, b1, flagArr, out);
}